// Round 5
// baseline (292.335 us; speedup 1.0000x reference)
//
#include <hip/hip_runtime.h>
#include <stdint.h>

#define EDIM 1024
#define HNUM 16
#define HD   64
#define BB   2
#define SS   2048
#define MTOT (BB * SS)

typedef __attribute__((ext_vector_type(8))) __bf16 bf16x8;
typedef __attribute__((ext_vector_type(8))) short short8;
typedef __attribute__((ext_vector_type(4))) short short4v;
typedef __attribute__((ext_vector_type(4))) float f32x4;
typedef __attribute__((ext_vector_type(16))) float f32x16;

__device__ __forceinline__ short bfbits(float f) {
  __bf16 h = (__bf16)f;
  return __builtin_bit_cast(short, h);
}

__device__ __forceinline__ void gload16(const void* g, void* l) {
  __builtin_amdgcn_global_load_lds((const __attribute__((address_space(1))) void*)g,
                                   (__attribute__((address_space(3))) void*)l, 16, 0, 0);
}

// V^T key-column permutation: swap bits 2 and 3 (involution, keeps low 2 bits)
__device__ __forceinline__ int sigma_perm(int k) {
  return (k & ~0xC) | ((k & 4) << 1) | ((k & 8) >> 1);
}

// ---------------------------------------------------------------------------
// Fused prep: [0,6144) f32->bf16 casts of q/k/v; [6144,7168) weight
// transpose+cast; [7168,23552) mask bit-packing.
// ---------------------------------------------------------------------------
__global__ __launch_bounds__(256) void prep(
    const float* __restrict__ q, const float* __restrict__ k,
    const float* __restrict__ v, const float* __restrict__ Wqkv,
    const float* __restrict__ Wout, const int* __restrict__ mask,
    short* __restrict__ Qb, short* __restrict__ Kb, short* __restrict__ Vb,
    short* __restrict__ WqT, short* __restrict__ WkT, short* __restrict__ WvT,
    short* __restrict__ WoT, unsigned long long* __restrict__ pm) {
  __shared__ short L[64][80];
  const int bid = blockIdx.x, t = threadIdx.x;

  if (bid < 6144) {  // ---- casts ----
    const int which = bid >> 11;
    const int i = (bid & 2047) * 256 + t;
    const float* s = which == 0 ? q : (which == 1 ? k : v);
    short* d = which == 0 ? Qb : (which == 1 ? Kb : Vb);
    const float4* sp = (const float4*)s + (size_t)i * 2;
    float4 a = sp[0], b = sp[1];
    short8 r;
    r[0] = bfbits(a.x); r[1] = bfbits(a.y); r[2] = bfbits(a.z); r[3] = bfbits(a.w);
    r[4] = bfbits(b.x); r[5] = bfbits(b.y); r[6] = bfbits(b.z); r[7] = bfbits(b.w);
    *(short8*)(d + (size_t)i * 8) = r;
  } else if (bid < 7168) {  // ---- weight transpose+cast ----
    const int tb = bid - 6144;
    const int which = tb >> 8;
    const int k0 = ((tb >> 4) & 15) * 64, n0 = (tb & 15) * 64;
    const float* W = which == 3 ? Wout : Wqkv;
    const int ld = which == 3 ? EDIM : 3 * EDIM;
    const int col0 = which == 3 ? 0 : which * EDIM;
    short* D = which == 0 ? WqT : (which == 1 ? WkT : (which == 2 ? WvT : WoT));
    {
      const int kr = t >> 2, nc0 = (t & 3) * 16;
      #pragma unroll
      for (int u = 0; u < 4; ++u) {
        float4 f = *(const float4*)(W + (size_t)(k0 + kr) * ld + col0 + n0 + nc0 + u * 4);
        L[nc0 + u * 4 + 0][kr] = bfbits(f.x);
        L[nc0 + u * 4 + 1][kr] = bfbits(f.y);
        L[nc0 + u * 4 + 2][kr] = bfbits(f.z);
        L[nc0 + u * 4 + 3][kr] = bfbits(f.w);
      }
    }
    __syncthreads();
    {
      const int nr = t >> 2, kc = (t & 3) * 16;
      #pragma unroll
      for (int u = 0; u < 2; ++u) {
        short8 vv = *(const short8*)&L[nr][kc + u * 8];
        *(short8*)(D + (size_t)(n0 + nr) * EDIM + k0 + kc + u * 8) = vv;
      }
    }
  } else {  // ---- mask packing ----
    const int wid = (bid - 7168) * 4 + (t >> 6);
    const int lane = t & 63;
    const int qq = wid >> 5, kt = wid & 31;
    const int m = mask[(size_t)qq * SS + kt * 64 + lane];
    const unsigned long long b = __ballot(m != 0);
    if (lane == 0) pm[(size_t)qq * 32 + kt] = b;
  }
}

// ---------------------------------------------------------------------------
// bf16 MFMA GEMM body. BM=128, BN=32*NFR, BK=64, 4 waves (2x2).
// MODE 0: bf16 row-major out; MODE 1: f32 row-major out;
// MODE 2: bf16 V^T out [b][h][64][SS] with sigma column permutation.
// ---------------------------------------------------------------------------
template <int NFR, int MODE, typename OT>
__device__ __forceinline__ void gemm_body(
    const short* __restrict__ A, const short* __restrict__ Bt,
    const float* __restrict__ bias, OT* __restrict__ O,
    int m0, int n0, int K, int N, float scale, short* As, short* Bs) {
  const int t = threadIdx.x;
  const int w = t >> 6, l = t & 63;
  const int wr = w >> 1, wc = w & 1;
  const int lr4 = l >> 4, lc = l & 15;

  f32x4 acc[4][NFR] = {};
  const int srow = t >> 3;
  const int schunk = (t & 7) ^ (srow & 7);

  for (int k0 = 0; k0 < K; k0 += 64) {
    #pragma unroll
    for (int p = 0; p < 4; ++p)
      gload16(A + (size_t)(m0 + 32 * p + srow) * K + k0 + schunk * 8,
              As + p * 2048 + w * 512);
    #pragma unroll
    for (int p = 0; p < NFR; ++p)
      gload16(Bt + (size_t)(n0 + 32 * p + srow) * K + k0 + schunk * 8,
              Bs + p * 2048 + w * 512);
    __syncthreads();

    #pragma unroll
    for (int kf = 0; kf < 2; ++kf) {
      const int c = ((4 * kf + lr4) ^ (lc & 7)) * 8;
      bf16x8 a[4], bfr[NFR];
      #pragma unroll
      for (int i = 0; i < 4; ++i)
        a[i] = *(const bf16x8*)(As + (64 * wr + 16 * i + lc) * 64 + c);
      #pragma unroll
      for (int j = 0; j < NFR; ++j)
        bfr[j] = *(const bf16x8*)(Bs + (16 * NFR * wc + 16 * j + lc) * 64 + c);
      #pragma unroll
      for (int i = 0; i < 4; ++i)
        #pragma unroll
        for (int j = 0; j < NFR; ++j)
          acc[i][j] = __builtin_amdgcn_mfma_f32_16x16x32_bf16(a[i], bfr[j], acc[i][j], 0, 0, 0);
    }
    __syncthreads();
  }

  #pragma unroll
  for (int j = 0; j < NFR; ++j) {
    const int col = n0 + 16 * NFR * wc + 16 * j + lc;
    const float bv = bias[col];
    #pragma unroll
    for (int i = 0; i < 4; ++i) {
      const int rbase = m0 + 64 * wr + 16 * i + 4 * lr4;
      if constexpr (MODE == 2) {
        const int bidx = rbase >> 11, s = rbase & 2047;
        const int hh = col >> 6, dd = col & 63;
        short4v o;
        #pragma unroll
        for (int r = 0; r < 4; ++r) o[r] = bfbits((acc[i][j][r] + bv) * scale);
        *(short4v*)((short*)O + (((size_t)bidx * HNUM + hh) * 64 + dd) * SS +
                    (s & ~63) + sigma_perm(s & 63)) = o;
      } else {
        #pragma unroll
        for (int r = 0; r < 4; ++r) {
          float vv = (acc[i][j][r] + bv) * scale;
          if constexpr (MODE == 0)
            ((short*)O)[(size_t)(rbase + r) * N + col] = bfbits(vv);
          else
            ((float*)O)[(size_t)(rbase + r) * N + col] = vv;
        }
      }
    }
  }
}

// Fused QKV projection: blockIdx.y selects {Q,K,V} x n-tile. 768 blocks.
// Q pre-scaled by (1/sqrt(D))*log2(e); V stored transposed+sigma-permuted.
__global__ __launch_bounds__(256) void gemm_qkv(
    const short* __restrict__ Qb, const short* __restrict__ Kb,
    const short* __restrict__ Vb, const short* __restrict__ WqT,
    const short* __restrict__ WkT, const short* __restrict__ WvT,
    const float* __restrict__ bqkv, short* __restrict__ Qpj,
    short* __restrict__ Kpj, short* __restrict__ VT) {
  __shared__ short As[128 * 64];
  __shared__ short Bs[128 * 64];
  const int sel = blockIdx.y >> 3;
  const int n0 = (blockIdx.y & 7) * 128;
  const int m0 = blockIdx.x * 128;
  if (sel == 0)
    gemm_body<4, 0, short>(Qb, WqT, bqkv, Qpj, m0, n0, EDIM, EDIM,
                           0.125f * 1.44269504089f, As, Bs);
  else if (sel == 1)
    gemm_body<4, 0, short>(Kb, WkT, bqkv + EDIM, Kpj, m0, n0, EDIM, EDIM,
                           1.0f, As, Bs);
  else
    gemm_body<4, 2, short>(Vb, WvT, bqkv + 2 * EDIM, VT, m0, n0, EDIM, EDIM,
                           1.0f, As, Bs);
}

// Output projection: BN=64 -> 512 blocks, fp32 out.
__global__ __launch_bounds__(256) void gemm_out(
    const short* __restrict__ A, const short* __restrict__ Bt,
    const float* __restrict__ bias, float* __restrict__ O) {
  __shared__ short As[128 * 64];
  __shared__ short Bs[64 * 64];
  gemm_body<2, 1, float>(A, Bt, bias, O, blockIdx.x * 128, blockIdx.y * 64,
                         EDIM, EDIM, 1.0f, As, Bs);
}

// ---------------------------------------------------------------------------
// Flash attention, 32x32 MFMA. Block = (64 q) x h x b, 2 waves; wave w owns
// q-rows [32w,32w+32), each lane ONE q-row (col=lane&31). 64-key tiles,
// K [key][d] and V^T [d][sigma(key)] double-buffered via global_load_lds with
// XOR-chunk source pre-swizzle. P^T fragment = lane's own 32 softmax values
// in register order (sigma makes the PV B-frag lane-local & sequential).
// ---------------------------------------------------------------------------
__global__ __launch_bounds__(128) void attn_mfma(
    const short* __restrict__ Qp, const short* __restrict__ Kp,
    const short* __restrict__ VT, const unsigned long long* __restrict__ pmask,
    short* __restrict__ Ctx) {
  __shared__ short Ks[2][4096];
  __shared__ short Vt[2][4096];

  const int t = threadIdx.x, w = t >> 6, l = t & 63;
  const int l31 = l & 31, h32 = l >> 5;
  const int q0 = blockIdx.x * 64;
  const int h = blockIdx.y, b = blockIdx.z;
  const size_t hb = (size_t)b * SS * EDIM + (size_t)h * HD;
  const size_t hv = ((size_t)b * HNUM + h) * (size_t)64 * SS;
  const int qrow = q0 + 32 * w + l31;

  // Q B-fragments: qf[c] = Q[qrow][16c + 8*h32 .. +8]
  bf16x8 qf[4];
  #pragma unroll
  for (int c = 0; c < 4; ++c)
    qf[c] = *(const bf16x8*)(Qp + hb + (size_t)qrow * EDIM + 16 * c + 8 * h32);

  // hoisted swizzled LDS read offsets (halfwords) + row base
  int roff[4];
  #pragma unroll
  for (int c = 0; c < 4; ++c) roff[c] = ((2 * c + h32) ^ (l & 7)) * 8;
  const int rowb = l31 * 64;

  // staging geometry: 8 rows/call, chunk pre-swizzle on global source
  const int sr = l >> 3;
  const int sc = (l & 7) ^ sr;
  const short* ksrc = Kp + hb + (size_t)(32 * w + sr) * EDIM + sc * 8;
  const short* vsrc = VT + hv + (size_t)(32 * w + sr) * SS + sc * 8;
  const int ldst = w * 2048;

  // ---- prologue: stage tile 0 ----
  #pragma unroll
  for (int p = 0; p < 4; ++p) {
    gload16(ksrc + (size_t)(8 * p) * EDIM, &Ks[0][ldst + p * 512]);
    gload16(vsrc + (size_t)(8 * p) * SS,  &Vt[0][ldst + p * 512]);
  }
  ksrc += (size_t)64 * EDIM;
  vsrc += 64;
  __syncthreads();

  f32x16 accO[2] = {};
  float mrow = -1e30f, lrow = 0.f;
  const unsigned long long* pmp = pmask + (size_t)qrow * (SS / 64);
  const int NT = SS / 64;

  for (int kt = 0; kt < NT; ++kt) {
    const int cur = kt & 1, nxt = cur ^ 1;
    const unsigned long long pw = pmp[kt];
    if (kt + 1 < NT) {  // async prefetch of next tile
      #pragma unroll
      for (int p = 0; p < 4; ++p) {
        gload16(ksrc + (size_t)(8 * p) * EDIM, &Ks[nxt][ldst + p * 512]);
        gload16(vsrc + (size_t)(8 * p) * SS,  &Vt[nxt][ldst + p * 512]);
      }
      ksrc += (size_t)64 * EDIM;
      vsrc += 64;
    }

    // ---- S^T = K Q^T : keys 32T+l31, one q-row per lane ----
    f32x16 sacc[2] = {};
    #pragma unroll
    for (int c = 0; c < 4; ++c) {
      bf16x8 ka = *(const bf16x8*)(&Ks[cur][rowb + roff[c]]);
      bf16x8 kb = *(const bf16x8*)(&Ks[cur][2048 + rowb + roff[c]]);
      sacc[0] = __builtin_amdgcn_mfma_f32_32x32x16_bf16(ka, qf[c], sacc[0], 0, 0, 0);
      sacc[1] = __builtin_amdgcn_mfma_f32_32x32x16_bf16(kb, qf[c], sacc[1], 0, 0, 0);
    }

    // ---- running max (unmasked, exact for softmax) ----
    float mA = -1e30f, mB = -1e30f;
    #pragma unroll
    for (int T = 0; T < 2; ++T)
      #pragma unroll
      for (int g = 0; g < 4; ++g) {
        mA = fmaxf(mA, fmaxf(sacc[T][4 * g + 0], sacc[T][4 * g + 1]));
        mB = fmaxf(mB, fmaxf(sacc[T][4 * g + 2], sacc[T][4 * g + 3]));
      }
    float mt = fmaxf(mA, mB);
    mt = fmaxf(mt, __shfl_xor(mt, 32, 64));

    if (__any(mt > mrow + 7.0f)) {  // defer-max rescale (rare)
      const float mn = fmaxf(mrow, mt);
      const float scl = exp2f(mrow - mn);
      mrow = mn;
      lrow *= scl;
      #pragma unroll
      for (int dt = 0; dt < 2; ++dt)
        #pragma unroll
        for (int r = 0; r < 16; ++r) accO[dt][r] *= scl;
    }

    // ---- P = mask ? exp2(s-m) : 0, packed straight into PV B-frags ----
    const unsigned long long pwh = pw >> (4 * h32);
    float ls = 0.f;
    union { unsigned u[4]; bf16x8 v; } pk[4];
    #pragma unroll
    for (int kc = 0; kc < 4; ++kc) {
      const int T = kc >> 1, rb = 8 * (kc & 1);
      #pragma unroll
      for (int wd = 0; wd < 4; ++wd) {
        const int r0 = rb + 2 * wd, r1 = r0 + 1;
        const int bit0 = 32 * T + 8 * (r0 >> 2) + (r0 & 3);
        const int bit1 = 32 * T + 8 * (r1 >> 2) + (r1 & 3);
        const float e0 = exp2f(sacc[T][r0] - mrow);
        const float e1 = exp2f(sacc[T][r1] - mrow);
        const float p0 = ((pwh >> bit0) & 1ull) ? e0 : 0.f;
        const float p1 = ((pwh >> bit1) & 1ull) ? e1 : 0.f;
        ls += p0 + p1;
        const unsigned b0 = (unsigned short)__builtin_bit_cast(unsigned short, (__bf16)p0);
        const unsigned b1 = (unsigned short)__builtin_bit_cast(unsigned short, (__bf16)p1);
        pk[kc].u[wd] = b0 | (b1 << 16);
      }
    }
    ls += __shfl_xor(ls, 32, 64);
    lrow += ls;

    // ---- O^T += V^T P^T ----
    #pragma unroll
    for (int kc = 0; kc < 4; ++kc) {
      bf16x8 va = *(const bf16x8*)(&Vt[cur][rowb + roff[kc]]);
      bf16x8 vb = *(const bf16x8*)(&Vt[cur][2048 + rowb + roff[kc]]);
      accO[0] = __builtin_amdgcn_mfma_f32_32x32x16_bf16(va, pk[kc].v, accO[0], 0, 0, 0);
      accO[1] = __builtin_amdgcn_mfma_f32_32x32x16_bf16(vb, pk[kc].v, accO[1], 0, 0, 0);
    }
    __syncthreads();  // drains prefetch gloads; next tile ready
  }

  // ---- epilogue: O[q][d], d = 32dt + 8g + 4h32 + r ----
  const float inv = 1.f / lrow;
  #pragma unroll
  for (int dt = 0; dt < 2; ++dt)
    #pragma unroll
    for (int g = 0; g < 4; ++g) {
      short4v o;
      #pragma unroll
      for (int r = 0; r < 4; ++r) o[r] = bfbits(accO[dt][4 * g + r] * inv);
      *(short4v*)(Ctx + hb + (size_t)qrow * EDIM + 32 * dt + 8 * g + 4 * h32) = o;
    }
}

// ---------------------------------------------------------------------------
extern "C" void kernel_launch(void* const* d_in, const int* in_sizes, int n_in,
                              void* d_out, int out_size, void* d_ws, size_t ws_size,
                              hipStream_t stream) {
  const float* q    = (const float*)d_in[0];
  const float* k    = (const float*)d_in[1];
  const float* v    = (const float*)d_in[2];
  const int*   mask = (const int*)d_in[3];
  const float* Wqkv = (const float*)d_in[4];
  const float* bqkv = (const float*)d_in[5];
  const float* Wout = (const float*)d_in[6];
  const float* bout = (const float*)d_in[7];
  float* out = (float*)d_out;

  const size_t mat = (size_t)MTOT * EDIM;   // 4M elements
  const size_t wmat = (size_t)EDIM * EDIM;  // 1M elements
  short* Qb  = (short*)d_ws;
  short* Kb  = Qb + mat;
  short* Vb  = Kb + mat;
  short* WqT = Vb + mat;
  short* WkT = WqT + wmat;
  short* WvT = WkT + wmat;
  short* WoT = WvT + wmat;
  short* Qpj = WoT + wmat;
  short* Kpj = Qpj + mat;
  short* VT  = Kpj + mat;   // [B][H][64][SS] transposed+permuted V
  short* Ctx = VT + mat;
  unsigned long long* pm = (unsigned long long*)(Ctx + mat);  // 512 KB

  prep<<<dim3(23552), 256, 0, stream>>>(q, k, v, Wqkv, Wout, mask,
                                        Qb, Kb, Vb, WqT, WkT, WvT, WoT, pm);

  gemm_qkv<<<dim3(MTOT / 128, 24), 256, 0, stream>>>(Qb, Kb, Vb, WqT, WkT, WvT,
                                                     bqkv, Qpj, Kpj, VT);

  attn_mfma<<<dim3(SS / 64, HNUM, BB), 128, 0, stream>>>(Qpj, Kpj, VT, pm, Ctx);

  gemm_out<<<dim3(MTOT / 128, EDIM / 64), 256, 0, stream>>>(Ctx, WoT, bout, out);
}

// Round 6
// 280.735 us; speedup vs baseline: 1.0413x; 1.0413x over previous
//
#include <hip/hip_runtime.h>
#include <stdint.h>

#define EDIM 1024
#define HNUM 16
#define HD   64
#define BB   2
#define SS   2048
#define MTOT (BB * SS)

typedef __attribute__((ext_vector_type(8))) __bf16 bf16x8;
typedef __attribute__((ext_vector_type(8))) short short8;
typedef __attribute__((ext_vector_type(4))) short short4v;
typedef __attribute__((ext_vector_type(4))) float f32x4;
typedef __attribute__((ext_vector_type(16))) float f32x16;

__device__ __forceinline__ short bfbits(float f) {
  __bf16 h = (__bf16)f;
  return __builtin_bit_cast(short, h);
}

__device__ __forceinline__ void gload16(const void* g, void* l) {
  __builtin_amdgcn_global_load_lds((const __attribute__((address_space(1))) void*)g,
                                   (__attribute__((address_space(3))) void*)l, 16, 0, 0);
}

// V^T key-column permutation: swap bits 2 and 3 (involution, keeps low 2 bits)
__device__ __forceinline__ int sigma_perm(int k) {
  return (k & ~0xC) | ((k & 4) << 1) | ((k & 8) >> 1);
}

// ---------------------------------------------------------------------------
// Fused prep: [0,6144) f32->bf16 casts of q/k/v; [6144,7168) weight
// transpose+cast; [7168,23552) mask bit-packing.
// ---------------------------------------------------------------------------
__global__ __launch_bounds__(256) void prep(
    const float* __restrict__ q, const float* __restrict__ k,
    const float* __restrict__ v, const float* __restrict__ Wqkv,
    const float* __restrict__ Wout, const int* __restrict__ mask,
    short* __restrict__ Qb, short* __restrict__ Kb, short* __restrict__ Vb,
    short* __restrict__ WqT, short* __restrict__ WkT, short* __restrict__ WvT,
    short* __restrict__ WoT, unsigned long long* __restrict__ pm) {
  __shared__ short L[64][80];
  const int bid = blockIdx.x, t = threadIdx.x;

  if (bid < 6144) {  // ---- casts ----
    const int which = bid >> 11;
    const int i = (bid & 2047) * 256 + t;
    const float* s = which == 0 ? q : (which == 1 ? k : v);
    short* d = which == 0 ? Qb : (which == 1 ? Kb : Vb);
    const float4* sp = (const float4*)s + (size_t)i * 2;
    float4 a = sp[0], b = sp[1];
    short8 r;
    r[0] = bfbits(a.x); r[1] = bfbits(a.y); r[2] = bfbits(a.z); r[3] = bfbits(a.w);
    r[4] = bfbits(b.x); r[5] = bfbits(b.y); r[6] = bfbits(b.z); r[7] = bfbits(b.w);
    *(short8*)(d + (size_t)i * 8) = r;
  } else if (bid < 7168) {  // ---- weight transpose+cast ----
    const int tb = bid - 6144;
    const int which = tb >> 8;
    const int k0 = ((tb >> 4) & 15) * 64, n0 = (tb & 15) * 64;
    const float* W = which == 3 ? Wout : Wqkv;
    const int ld = which == 3 ? EDIM : 3 * EDIM;
    const int col0 = which == 3 ? 0 : which * EDIM;
    short* D = which == 0 ? WqT : (which == 1 ? WkT : (which == 2 ? WvT : WoT));
    {
      const int kr = t >> 2, nc0 = (t & 3) * 16;
      #pragma unroll
      for (int u = 0; u < 4; ++u) {
        float4 f = *(const float4*)(W + (size_t)(k0 + kr) * ld + col0 + n0 + nc0 + u * 4);
        L[nc0 + u * 4 + 0][kr] = bfbits(f.x);
        L[nc0 + u * 4 + 1][kr] = bfbits(f.y);
        L[nc0 + u * 4 + 2][kr] = bfbits(f.z);
        L[nc0 + u * 4 + 3][kr] = bfbits(f.w);
      }
    }
    __syncthreads();
    {
      const int nr = t >> 2, kc = (t & 3) * 16;
      #pragma unroll
      for (int u = 0; u < 2; ++u) {
        short8 vv = *(const short8*)&L[nr][kc + u * 8];
        *(short8*)(D + (size_t)(n0 + nr) * EDIM + k0 + kc + u * 8) = vv;
      }
    }
  } else {  // ---- mask packing ----
    const int wid = (bid - 7168) * 4 + (t >> 6);
    const int lane = t & 63;
    const int qq = wid >> 5, kt = wid & 31;
    const int m = mask[(size_t)qq * SS + kt * 64 + lane];
    const unsigned long long b = __ballot(m != 0);
    if (lane == 0) pm[(size_t)qq * 32 + kt] = b;
  }
}

// ---------------------------------------------------------------------------
// bf16 MFMA GEMM body. BM=128, BN=32*NFR, BK=64, 4 waves (2x2).
// MODE 0: bf16 row-major out; MODE 1: f32 row-major out;
// MODE 2: bf16 V^T out [b][h][64][SS] with sigma column permutation.
// ---------------------------------------------------------------------------
template <int NFR, int MODE, typename OT>
__device__ __forceinline__ void gemm_body(
    const short* __restrict__ A, const short* __restrict__ Bt,
    const float* __restrict__ bias, OT* __restrict__ O,
    int m0, int n0, int K, int N, float scale, short* As, short* Bs) {
  const int t = threadIdx.x;
  const int w = t >> 6, l = t & 63;
  const int wr = w >> 1, wc = w & 1;
  const int lr4 = l >> 4, lc = l & 15;

  f32x4 acc[4][NFR] = {};
  const int srow = t >> 3;
  const int schunk = (t & 7) ^ (srow & 7);

  for (int k0 = 0; k0 < K; k0 += 64) {
    #pragma unroll
    for (int p = 0; p < 4; ++p)
      gload16(A + (size_t)(m0 + 32 * p + srow) * K + k0 + schunk * 8,
              As + p * 2048 + w * 512);
    #pragma unroll
    for (int p = 0; p < NFR; ++p)
      gload16(Bt + (size_t)(n0 + 32 * p + srow) * K + k0 + schunk * 8,
              Bs + p * 2048 + w * 512);
    __syncthreads();

    #pragma unroll
    for (int kf = 0; kf < 2; ++kf) {
      const int c = ((4 * kf + lr4) ^ (lc & 7)) * 8;
      bf16x8 a[4], bfr[NFR];
      #pragma unroll
      for (int i = 0; i < 4; ++i)
        a[i] = *(const bf16x8*)(As + (64 * wr + 16 * i + lc) * 64 + c);
      #pragma unroll
      for (int j = 0; j < NFR; ++j)
        bfr[j] = *(const bf16x8*)(Bs + (16 * NFR * wc + 16 * j + lc) * 64 + c);
      #pragma unroll
      for (int i = 0; i < 4; ++i)
        #pragma unroll
        for (int j = 0; j < NFR; ++j)
          acc[i][j] = __builtin_amdgcn_mfma_f32_16x16x32_bf16(a[i], bfr[j], acc[i][j], 0, 0, 0);
    }
    __syncthreads();
  }

  #pragma unroll
  for (int j = 0; j < NFR; ++j) {
    const int col = n0 + 16 * NFR * wc + 16 * j + lc;
    const float bv = bias[col];
    #pragma unroll
    for (int i = 0; i < 4; ++i) {
      const int rbase = m0 + 64 * wr + 16 * i + 4 * lr4;
      if constexpr (MODE == 2) {
        const int bidx = rbase >> 11, s = rbase & 2047;
        const int hh = col >> 6, dd = col & 63;
        short4v o;
        #pragma unroll
        for (int r = 0; r < 4; ++r) o[r] = bfbits((acc[i][j][r] + bv) * scale);
        *(short4v*)((short*)O + (((size_t)bidx * HNUM + hh) * 64 + dd) * SS +
                    (s & ~63) + sigma_perm(s & 63)) = o;
      } else {
        #pragma unroll
        for (int r = 0; r < 4; ++r) {
          float vv = (acc[i][j][r] + bv) * scale;
          if constexpr (MODE == 0)
            ((short*)O)[(size_t)(rbase + r) * N + col] = bfbits(vv);
          else
            ((float*)O)[(size_t)(rbase + r) * N + col] = vv;
        }
      }
    }
  }
}

// Fused QKV projection: blockIdx.y selects {Q,K,V} x n-tile. 768 blocks.
// Q pre-scaled by (1/sqrt(D))*log2(e); V stored transposed+sigma-permuted.
__global__ __launch_bounds__(256) void gemm_qkv(
    const short* __restrict__ Qb, const short* __restrict__ Kb,
    const short* __restrict__ Vb, const short* __restrict__ WqT,
    const short* __restrict__ WkT, const short* __restrict__ WvT,
    const float* __restrict__ bqkv, short* __restrict__ Qpj,
    short* __restrict__ Kpj, short* __restrict__ VT) {
  __shared__ short As[128 * 64];
  __shared__ short Bs[128 * 64];
  const int sel = blockIdx.y >> 3;
  const int n0 = (blockIdx.y & 7) * 128;
  const int m0 = blockIdx.x * 128;
  if (sel == 0)
    gemm_body<4, 0, short>(Qb, WqT, bqkv, Qpj, m0, n0, EDIM, EDIM,
                           0.125f * 1.44269504089f, As, Bs);
  else if (sel == 1)
    gemm_body<4, 0, short>(Kb, WkT, bqkv + EDIM, Kpj, m0, n0, EDIM, EDIM,
                           1.0f, As, Bs);
  else
    gemm_body<4, 2, short>(Vb, WvT, bqkv + 2 * EDIM, VT, m0, n0, EDIM, EDIM,
                           1.0f, As, Bs);
}

// Output projection: BN=64 -> 512 blocks, fp32 out.
__global__ __launch_bounds__(256) void gemm_out(
    const short* __restrict__ A, const short* __restrict__ Bt,
    const float* __restrict__ bias, float* __restrict__ O) {
  __shared__ short As[128 * 64];
  __shared__ short Bs[64 * 64];
  gemm_body<2, 1, float>(A, Bt, bias, O, blockIdx.x * 128, blockIdx.y * 64,
                         EDIM, EDIM, 1.0f, As, Bs);
}

// ---------------------------------------------------------------------------
// Flash attention, 32x32 MFMA. 256 threads / 4 waves; q-block 128; wave w
// owns q-rows [32w,32w+32), each lane ONE q-row. 64-key tiles, K [key][d]
// and V^T [d][sigma(key)] double-buffered via global_load_lds.
// LDS swizzle S(row) = (row&7) ^ ((row>>3)&3)<<1 applied on the GLOBAL
// source chunk (linear LDS dest): conflict-free for stride-8 lane phases.
// 1D grid 512, XCD-contiguous remap (4 head-instances per XCD -> L2-fit KV).
// ---------------------------------------------------------------------------
__global__ __launch_bounds__(256) void attn_mfma(
    const short* __restrict__ Qp, const short* __restrict__ Kp,
    const short* __restrict__ VT, const unsigned long long* __restrict__ pmask,
    short* __restrict__ Ctx) {
  __shared__ short Ks[2][4096];
  __shared__ short Vt[2][4096];

  const int t = threadIdx.x, w = t >> 6, l = t & 63;
  const int l31 = l & 31, h32 = l >> 5;
  // XCD-contiguous bijective remap of the 1D grid (512 = 8 * 64)
  const int lin = (blockIdx.x & 7) * 64 + (blockIdx.x >> 3);
  const int qt = lin & 15, h = (lin >> 4) & 15, b = lin >> 8;
  const int q0 = qt * 128;
  const size_t hb = (size_t)b * SS * EDIM + (size_t)h * HD;
  const size_t hv = ((size_t)b * HNUM + h) * (size_t)64 * SS;
  const int qrow = q0 + 32 * w + l31;

  // Q B-fragments: qf[c] = Q[qrow][16c + 8*h32 .. +8]
  bf16x8 qf[4];
  #pragma unroll
  for (int c = 0; c < 4; ++c)
    qf[c] = *(const bf16x8*)(Qp + hb + (size_t)qrow * EDIM + 16 * c + 8 * h32);

  // swizzled LDS read offsets: chunk = (2c+h32) ^ (l&7) ^ 2*((l31>>3)&3)
  // (identical for row and row+32 since bit2 of row>>3 is masked out)
  const int rswz = ((l31 >> 3) & 3) << 1;
  int roff[4];
  #pragma unroll
  for (int c = 0; c < 4; ++c) roff[c] = (((2 * c + h32) ^ (l & 7) ^ rswz) * 8);
  const int rowb = l31 * 64;

  // staging: wave w, call p covers tile rows [8*g2, 8*g2+8), g2 = 2w+p.
  // lane l -> row 8*g2 + (l>>3), LDS chunk l&7 holds global chunk
  // (l&7) ^ (l>>3) ^ ((g2&3)<<1).
  const int sr8 = l >> 3;
  const int g2a = 2 * w, g2b = 2 * w + 1;
  const int sca = (l & 7) ^ sr8 ^ ((g2a & 3) << 1);
  const int scb = (l & 7) ^ sr8 ^ ((g2b & 3) << 1);
  const short* ksA = Kp + hb + (size_t)(8 * g2a + sr8) * EDIM + sca * 8;
  const short* ksB = Kp + hb + (size_t)(8 * g2b + sr8) * EDIM + scb * 8;
  const short* vsA = VT + hv + (size_t)(8 * g2a + sr8) * SS + sca * 8;
  const short* vsB = VT + hv + (size_t)(8 * g2b + sr8) * SS + scb * 8;
  const int ldA = g2a * 512, ldB = g2b * 512;

  // ---- prologue: stage tile 0 ----
  gload16(ksA, &Ks[0][ldA + l * 8]);
  gload16(ksB, &Ks[0][ldB + l * 8]);
  gload16(vsA, &Vt[0][ldA + l * 8]);
  gload16(vsB, &Vt[0][ldB + l * 8]);
  ksA += (size_t)64 * EDIM; ksB += (size_t)64 * EDIM;
  vsA += 64; vsB += 64;
  __syncthreads();

  f32x16 accO[2] = {};
  float mrow = -1e30f, lrow = 0.f;
  const unsigned long long* pmp = pmask + (size_t)qrow * (SS / 64);
  const int NT = SS / 64;

  for (int kt = 0; kt < NT; ++kt) {
    const int cur = kt & 1, nxt = cur ^ 1;
    const unsigned long long pw = pmp[kt];
    if (kt + 1 < NT) {  // async prefetch of next tile
      gload16(ksA, &Ks[nxt][ldA + l * 8]);
      gload16(ksB, &Ks[nxt][ldB + l * 8]);
      gload16(vsA, &Vt[nxt][ldA + l * 8]);
      gload16(vsB, &Vt[nxt][ldB + l * 8]);
      ksA += (size_t)64 * EDIM; ksB += (size_t)64 * EDIM;
      vsA += 64; vsB += 64;
    }

    // ---- S^T = K Q^T : keys 32T+l31, one q-row per lane ----
    f32x16 sacc[2] = {};
    __builtin_amdgcn_s_setprio(1);
    #pragma unroll
    for (int c = 0; c < 4; ++c) {
      bf16x8 ka = *(const bf16x8*)(&Ks[cur][rowb + roff[c]]);
      bf16x8 kb = *(const bf16x8*)(&Ks[cur][2048 + rowb + roff[c]]);
      sacc[0] = __builtin_amdgcn_mfma_f32_32x32x16_bf16(ka, qf[c], sacc[0], 0, 0, 0);
      sacc[1] = __builtin_amdgcn_mfma_f32_32x32x16_bf16(kb, qf[c], sacc[1], 0, 0, 0);
    }
    __builtin_amdgcn_s_setprio(0);

    // ---- running max (unmasked, exact for softmax) ----
    float mA = -1e30f, mB = -1e30f;
    #pragma unroll
    for (int T = 0; T < 2; ++T)
      #pragma unroll
      for (int g = 0; g < 4; ++g) {
        mA = fmaxf(mA, fmaxf(sacc[T][4 * g + 0], sacc[T][4 * g + 1]));
        mB = fmaxf(mB, fmaxf(sacc[T][4 * g + 2], sacc[T][4 * g + 3]));
      }
    float mt = fmaxf(mA, mB);
    mt = fmaxf(mt, __shfl_xor(mt, 32, 64));

    if (__any(mt > mrow + 7.0f)) {  // defer-max rescale (rare)
      const float mn = fmaxf(mrow, mt);
      const float scl = exp2f(mrow - mn);
      mrow = mn;
      lrow *= scl;
      #pragma unroll
      for (int dt = 0; dt < 2; ++dt)
        #pragma unroll
        for (int r = 0; r < 16; ++r) accO[dt][r] *= scl;
    }

    // ---- P = mask ? exp2(s-m) : 0, packed straight into PV B-frags ----
    const unsigned long long pwh = pw >> (4 * h32);
    float ls = 0.f;
    union { unsigned u[4]; bf16x8 v; } pk[4];
    #pragma unroll
    for (int kc = 0; kc < 4; ++kc) {
      const int T = kc >> 1, rb = 8 * (kc & 1);
      #pragma unroll
      for (int wd = 0; wd < 4; ++wd) {
        const int r0 = rb + 2 * wd, r1 = r0 + 1;
        const int bit0 = 32 * T + 8 * (r0 >> 2) + (r0 & 3);
        const int bit1 = 32 * T + 8 * (r1 >> 2) + (r1 & 3);
        const float e0 = exp2f(sacc[T][r0] - mrow);
        const float e1 = exp2f(sacc[T][r1] - mrow);
        const float p0 = ((pwh >> bit0) & 1ull) ? e0 : 0.f;
        const float p1 = ((pwh >> bit1) & 1ull) ? e1 : 0.f;
        ls += p0 + p1;
        const unsigned b0 = (unsigned short)__builtin_bit_cast(unsigned short, (__bf16)p0);
        const unsigned b1 = (unsigned short)__builtin_bit_cast(unsigned short, (__bf16)p1);
        pk[kc].u[wd] = b0 | (b1 << 16);
      }
    }
    ls += __shfl_xor(ls, 32, 64);
    lrow += ls;

    // ---- O^T += V^T P^T ----
    __builtin_amdgcn_s_setprio(1);
    #pragma unroll
    for (int kc = 0; kc < 4; ++kc) {
      bf16x8 va = *(const bf16x8*)(&Vt[cur][rowb + roff[kc]]);
      bf16x8 vb = *(const bf16x8*)(&Vt[cur][2048 + rowb + roff[kc]]);
      accO[0] = __builtin_amdgcn_mfma_f32_32x32x16_bf16(va, pk[kc].v, accO[0], 0, 0, 0);
      accO[1] = __builtin_amdgcn_mfma_f32_32x32x16_bf16(vb, pk[kc].v, accO[1], 0, 0, 0);
    }
    __builtin_amdgcn_s_setprio(0);
    __syncthreads();  // drains prefetch gloads; next tile ready
  }

  // ---- epilogue: O[q][d], d = 32dt + 8g + 4h32 + r ----
  const float inv = 1.f / lrow;
  #pragma unroll
  for (int dt = 0; dt < 2; ++dt)
    #pragma unroll
    for (int g = 0; g < 4; ++g) {
      short4v o;
      #pragma unroll
      for (int r = 0; r < 4; ++r) o[r] = bfbits(accO[dt][4 * g + r] * inv);
      *(short4v*)(Ctx + hb + (size_t)qrow * EDIM + 32 * dt + 8 * g + 4 * h32) = o;
    }
}

// ---------------------------------------------------------------------------
extern "C" void kernel_launch(void* const* d_in, const int* in_sizes, int n_in,
                              void* d_out, int out_size, void* d_ws, size_t ws_size,
                              hipStream_t stream) {
  const float* q    = (const float*)d_in[0];
  const float* k    = (const float*)d_in[1];
  const float* v    = (const float*)d_in[2];
  const int*   mask = (const int*)d_in[3];
  const float* Wqkv = (const float*)d_in[4];
  const float* bqkv = (const float*)d_in[5];
  const float* Wout = (const float*)d_in[6];
  const float* bout = (const float*)d_in[7];
  float* out = (float*)d_out;

  const size_t mat = (size_t)MTOT * EDIM;   // 4M elements
  const size_t wmat = (size_t)EDIM * EDIM;  // 1M elements
  short* Qb  = (short*)d_ws;
  short* Kb  = Qb + mat;
  short* Vb  = Kb + mat;
  short* WqT = Vb + mat;
  short* WkT = WqT + wmat;
  short* WvT = WkT + wmat;
  short* WoT = WvT + wmat;
  short* Qpj = WoT + wmat;
  short* Kpj = Qpj + mat;
  short* VT  = Kpj + mat;   // [B][H][64][SS] transposed+permuted V
  short* Ctx = VT + mat;
  unsigned long long* pm = (unsigned long long*)(Ctx + mat);  // 512 KB

  prep<<<dim3(23552), 256, 0, stream>>>(q, k, v, Wqkv, Wout, mask,
                                        Qb, Kb, Vb, WqT, WkT, WvT, WoT, pm);

  gemm_qkv<<<dim3(MTOT / 128, 24), 256, 0, stream>>>(Qb, Kb, Vb, WqT, WkT, WvT,
                                                     bqkv, Qpj, Kpj, VT);

  attn_mfma<<<dim3(512), 256, 0, stream>>>(Qpj, Kpj, VT, pm, Ctx);

  gemm_out<<<dim3(MTOT / 128, EDIM / 64), 256, 0, stream>>>(Ctx, WoT, bout, out);
}